// Round 1
// baseline (218.291 us; speedup 1.0000x reference)
//
#include <hip/hip_runtime.h>
#include <hip/hip_bf16.h>

// Problem constants
#define SRC   16384      // 128*128 source pixels
#define DCH   64         // channels
#define NCLS  19         // classes
#define NPAIR (NCLS*DCH) // 1216 (c,d) pairs

// ---------------------------------------------------------------------------
// K1: per-source-pixel class counts. Each source pixel covers a 4x4 block of
// the 512x512 label map. cnt[c*SRC + s] = #subpixels with label c (0..16).
// ---------------------------------------------------------------------------
__global__ __launch_bounds__(256) void hl_count_kernel(
    const int* __restrict__ label, unsigned char* __restrict__ cnt)
{
    int s  = blockIdx.x * 256 + threadIdx.x;   // 64 blocks x 256 = 16384
    int sy = s >> 7, sx = s & 127;
    const int4* lab4 = (const int4*)label;
    int l[16];
#pragma unroll
    for (int r = 0; r < 4; r++) {
        int4 v = lab4[(4 * sy + r) * 128 + sx];   // label[(4sy+r)*512 + 4sx ..+3]
        l[4 * r + 0] = v.x; l[4 * r + 1] = v.y;
        l[4 * r + 2] = v.z; l[4 * r + 3] = v.w;
    }
#pragma unroll
    for (int c = 0; c < NCLS; c++) {
        int cc = 0;
#pragma unroll
        for (int j = 0; j < 16; j++) cc += (l[j] == c) ? 1 : 0;
        cnt[c * SRC + s] = (unsigned char)cc;
    }
}

// ---------------------------------------------------------------------------
// K2: per-(class,channel) moments. One wave per (c,d): S1 = sum cnt*x,
// S2 = sum cnt*x^2 (double accumulation), n[c] = sum cnt (written by d==0).
// No atomics: exactly one wave owns each output slot.
// ---------------------------------------------------------------------------
__global__ __launch_bounds__(256) void hl_moments_kernel(
    const float* __restrict__ feature, const unsigned char* __restrict__ cnt,
    double* __restrict__ S1, double* __restrict__ S2, int* __restrict__ ncls)
{
    int w    = (blockIdx.x * 256 + threadIdx.x) >> 6;  // 304 blocks -> 1216 waves
    int lane = threadIdx.x & 63;
    int c = w >> 6, d = w & 63;

    const unsigned char* cp = cnt + c * SRC;
    const float*         fp = feature + d * SRC;

    double s1 = 0.0, s2 = 0.0;
    int    nc = 0;
    for (int s = lane; s < SRC; s += 64) {
        int    cv = cp[s];
        double xd = (double)fp[s];
        double w0 = (double)cv;
        s1 += w0 * xd;
        s2 += w0 * xd * xd;
        nc += cv;
    }
#pragma unroll
    for (int o = 32; o > 0; o >>= 1) {
        s1 += __shfl_down(s1, o);
        s2 += __shfl_down(s2, o);
        nc += __shfl_down(nc, o);
    }
    if (lane == 0) {
        S1[w] = s1;
        S2[w] = s2;
        if (d == 0) ncls[c] = nc;
    }
}

// ---------------------------------------------------------------------------
// K4: KDE. One wave per (c,d). u = (x-mu)/std; weight exp(-12.5 (k-u)^2).
// Only the 3 bins nearest round(u) matter (next is exp(-28) ~ 7e-13 rel).
// fp32 register accumulators, wave shuffle reduce, direct store.
// ---------------------------------------------------------------------------
__global__ __launch_bounds__(256) void hl_kde_kernel(
    const float* __restrict__ feature, const unsigned char* __restrict__ cnt,
    const double* __restrict__ S1d, const double* __restrict__ S2d,
    const int* __restrict__ ncls, float* __restrict__ sample)
{
    int w    = (blockIdx.x * 256 + threadIdx.x) >> 6;
    int lane = threadIdx.x & 63;
    int c = w >> 6, d = w & 63;

    int    n     = ncls[c];
    double nsafe = (n > 0) ? (double)n : 1.0;
    double s1 = S1d[w], s2 = S2d[w];
    double mu  = s1 / nsafe;
    double var = (s2 - 2.0 * mu * s1 + mu * mu * (double)n) / nsafe + 1e-10;
    float  muf  = (float)mu;
    float  istd = (float)(1.0 / sqrt(var));

    const unsigned char* cp = cnt + c * SRC;
    const float*         fp = feature + d * SRC;

    float acc[7] = {0.f, 0.f, 0.f, 0.f, 0.f, 0.f, 0.f};

    for (int s = lane; s < SRC; s += 64) {
        int   cv = cp[s];
        float x  = fp[s];
        float u  = (x - muf) * istd;
        float k0 = rintf(u);
        k0 = fminf(fmaxf(k0, -4.f), 4.f);
        float cf = (float)cv;
        float tm = u - (k0 - 1.f);
        float t0 = u - k0;
        float tp = u - (k0 + 1.f);
        float wm = cf * __expf(-12.5f * tm * tm);
        float w0 = cf * __expf(-12.5f * t0 * t0);
        float wp = cf * __expf(-12.5f * tp * tp);
        int b = (int)k0 + 3;   // in [-1 .. 7]
#pragma unroll
        for (int j = 0; j < 7; j++) {
            float add = (j == b) ? w0 : ((j == b - 1) ? wm : ((j == b + 1) ? wp : 0.f));
            acc[j] += add;
        }
    }
#pragma unroll
    for (int j = 0; j < 7; j++) {
        float v = acc[j];
#pragma unroll
        for (int o = 32; o > 0; o >>= 1) v += __shfl_down(v, o);
        if (lane == 0) sample[w * 7 + j] = v;
    }
}

// ---------------------------------------------------------------------------
// K5: final loss. Normalize per-(c,d) 7-bin histogram, smooth-L1 vs fixed
// target, gate by n>=1000, average over active classes. Single block.
// ---------------------------------------------------------------------------
__global__ __launch_bounds__(512) void hl_loss_kernel(
    const float* __restrict__ sample, const int* __restrict__ ncls,
    float* __restrict__ out)
{
    int tid = threadIdx.x;

    // target: exp(-0.5 k^2)/Z  (the 1/sqrt(2 pi var) factor cancels in the
    // normalization). Compute in double for exactness.
    float targ[7];
    {
        double e[7], z = 0.0;
#pragma unroll
        for (int k = -3; k <= 3; k++) { e[k + 3] = exp(-0.5 * (double)(k * k)); z += e[k + 3]; }
#pragma unroll
        for (int j = 0; j < 7; j++) targ[j] = (float)(e[j] / z);
    }

    float lsum = 0.f, asum = 0.f;
    for (int p = tid; p < NPAIR; p += 512) {
        int c = p >> 6;
        int n = ncls[c];
        if (n < 1000) continue;             // inactive: contributes 0
        float sv[7], S = 0.f;
#pragma unroll
        for (int j = 0; j < 7; j++) { sv[j] = sample[p * 7 + j]; S += sv[j]; }
        float Ss = fmaxf(S, 1e-30f);
        float ps = 0.f;
#pragma unroll
        for (int j = 0; j < 7; j++) {
            float dd = fabsf(sv[j] / Ss - targ[j]);
            ps += (dd < 1.f) ? 0.5f * dd * dd : (dd - 0.5f);
        }
        lsum += ps;
        if ((p & 63) == 0) asum += 1.f;     // count each active class once (d==0)
    }

#pragma unroll
    for (int o = 32; o > 0; o >>= 1) {
        lsum += __shfl_down(lsum, o);
        asum += __shfl_down(asum, o);
    }
    __shared__ float lw[8], aw[8];
    int wid = tid >> 6;
    if ((tid & 63) == 0) { lw[wid] = lsum; aw[wid] = asum; }
    __syncthreads();
    if (tid == 0) {
        float L = 0.f, A = 0.f;
#pragma unroll
        for (int i = 0; i < 8; i++) { L += lw[i]; A += aw[i]; }
        out[0] = (A > 0.f) ? (L / 448.0f) / A : 0.0f;  // mean over D*7=448, /num_active
    }
}

// ---------------------------------------------------------------------------
extern "C" void kernel_launch(void* const* d_in, const int* in_sizes, int n_in,
                              void* d_out, int out_size, void* d_ws, size_t ws_size,
                              hipStream_t stream)
{
    const float* feature = (const float*)d_in[0];   // [1,64,128,128] fp32
    const int*   label   = (const int*)d_in[1];     // [1,1,512,512]  int32
    float*       out     = (float*)d_out;           // scalar fp32

    char* ws = (char*)d_ws;
    // workspace layout (all freshly written every call; poison-safe)
    unsigned char* cnt    = (unsigned char*)(ws);                 // 19*16384 = 311296 B
    double*        S1     = (double*)(ws + 311296);               // 1216*8 = 9728 B
    double*        S2     = (double*)(ws + 311296 + 9728);        // 9728 B
    int*           ncls   = (int*)(ws + 311296 + 2 * 9728);       // 76 B
    float*         sample = (float*)(ws + 311296 + 2 * 9728 + 128); // 1216*7*4 = 34048 B

    hl_count_kernel<<<SRC / 256, 256, 0, stream>>>(label, cnt);
    hl_moments_kernel<<<NPAIR / 4, 256, 0, stream>>>(feature, cnt, S1, S2, ncls);
    hl_kde_kernel<<<NPAIR / 4, 256, 0, stream>>>(feature, cnt, S1, S2, ncls, sample);
    hl_loss_kernel<<<1, 512, 0, stream>>>(sample, ncls, out);
}

// Round 2
// 110.002 us; speedup vs baseline: 1.9844x; 1.9844x over previous
//
#include <hip/hip_runtime.h>
#include <hip/hip_bf16.h>

// Problem constants
#define SRC   16384      // 128*128 source pixels
#define DCH   64         // channels
#define NCLS  19         // classes
#define NPAIR (NCLS*DCH) // 1216 (c,d) pairs

// ---------------------------------------------------------------------------
// K1: per-source-pixel class counts. Each source pixel covers a 4x4 block of
// the 512x512 label map. cnt[c*SRC + s] = #subpixels with label c (0..16).
// ---------------------------------------------------------------------------
__global__ __launch_bounds__(256) void hl_count_kernel(
    const int* __restrict__ label, unsigned char* __restrict__ cnt)
{
    int s  = blockIdx.x * 256 + threadIdx.x;   // 64 blocks x 256 = 16384
    int sy = s >> 7, sx = s & 127;
    const int4* lab4 = (const int4*)label;
    int l[16];
#pragma unroll
    for (int r = 0; r < 4; r++) {
        int4 v = lab4[(4 * sy + r) * 128 + sx];   // label[(4sy+r)*512 + 4sx ..+3]
        l[4 * r + 0] = v.x; l[4 * r + 1] = v.y;
        l[4 * r + 2] = v.z; l[4 * r + 3] = v.w;
    }
#pragma unroll
    for (int c = 0; c < NCLS; c++) {
        int cc = 0;
#pragma unroll
        for (int j = 0; j < 16; j++) cc += (l[j] == c) ? 1 : 0;
        cnt[c * SRC + s] = (unsigned char)cc;
    }
}

// ---------------------------------------------------------------------------
// K2: per-(class,channel) moments. One 1024-thread block (16 waves) per
// (c,d): each thread covers 16 pixels as 4x (float4 + packed-u8x4) loads.
// Double accumulation; shuffle + LDS reduce; no atomics.
// ---------------------------------------------------------------------------
__global__ __launch_bounds__(1024) void hl_moments_kernel(
    const float* __restrict__ feature, const unsigned char* __restrict__ cnt,
    double* __restrict__ S1, double* __restrict__ S2, int* __restrict__ ncls)
{
    int w = blockIdx.x;             // pair index 0..1215
    int c = w >> 6, d = w & 63;
    int tid = threadIdx.x;

    const float4*       fp4 = (const float4*)(feature + d * SRC);
    const unsigned int* cp4 = (const unsigned int*)(cnt + c * SRC);

    double s1 = 0.0, s2 = 0.0;
    int    nc = 0;
#pragma unroll
    for (int i = 0; i < 4; i++) {
        int g = i * 1024 + tid;      // 4096 groups of 4 pixels
        float4       x  = fp4[g];
        unsigned int cv = cp4[g];
        int c0 = cv & 255, c1 = (cv >> 8) & 255, c2 = (cv >> 16) & 255, c3 = cv >> 24;
        double x0 = x.x, x1 = x.y, x2 = x.z, x3 = x.w;
        s1 += c0 * x0 + c1 * x1 + c2 * x2 + c3 * x3;
        s2 += c0 * x0 * x0 + c1 * x1 * x1 + c2 * x2 * x2 + c3 * x3 * x3;
        nc += c0 + c1 + c2 + c3;
    }
#pragma unroll
    for (int o = 32; o > 0; o >>= 1) {
        s1 += __shfl_down(s1, o);
        s2 += __shfl_down(s2, o);
        nc += __shfl_down(nc, o);
    }
    __shared__ double ps1[16], ps2[16];
    __shared__ int    pn[16];
    int wid = tid >> 6;
    if ((tid & 63) == 0) { ps1[wid] = s1; ps2[wid] = s2; pn[wid] = nc; }
    __syncthreads();
    if (tid == 0) {
        double a = 0.0, b = 0.0; int n = 0;
#pragma unroll
        for (int i = 0; i < 16; i++) { a += ps1[i]; b += ps2[i]; n += pn[i]; }
        S1[w] = a; S2[w] = b;
        if (d == 0) ncls[c] = n;
    }
}

// ---------------------------------------------------------------------------
// K3: KDE. One 1024-thread block per (c,d). u = (x-mu)/std; all 7 bins
// evaluated unconditionally: acc[k] += cnt * exp2(C1*(u-k)^2),
// C1 = -12.5*log2(e). The 1/sqrt(2*pi*var_s) factor cancels in the
// downstream normalization. fp32 accumulators; shuffle + LDS reduce.
// ---------------------------------------------------------------------------
__global__ __launch_bounds__(1024) void hl_kde_kernel(
    const float* __restrict__ feature, const unsigned char* __restrict__ cnt,
    const double* __restrict__ S1d, const double* __restrict__ S2d,
    const int* __restrict__ ncls, float* __restrict__ sample)
{
    int w = blockIdx.x;
    int c = w >> 6, d = w & 63;
    int tid = threadIdx.x;

    __shared__ float sh_mu, sh_istd;
    if (tid == 0) {
        int    n     = ncls[c];
        double nsafe = (n > 0) ? (double)n : 1.0;
        double s1 = S1d[w], s2 = S2d[w];
        double mu  = s1 / nsafe;
        double var = (s2 - 2.0 * mu * s1 + mu * mu * (double)n) / nsafe + 1e-10;
        sh_mu   = (float)mu;
        sh_istd = (float)(1.0 / sqrt(var));
    }
    __syncthreads();
    float muf = sh_mu, istd = sh_istd;

    const float4*       fp4 = (const float4*)(feature + d * SRC);
    const unsigned int* cp4 = (const unsigned int*)(cnt + c * SRC);

    const float C1 = -18.033688011112042f;   // -12.5 * log2(e)
    float acc[7] = {0.f, 0.f, 0.f, 0.f, 0.f, 0.f, 0.f};

#pragma unroll
    for (int i = 0; i < 4; i++) {
        int g = i * 1024 + tid;
        float4       x  = fp4[g];
        unsigned int cv = cp4[g];
        float xs[4] = {x.x, x.y, x.z, x.w};
        float cf[4] = {(float)(cv & 255), (float)((cv >> 8) & 255),
                       (float)((cv >> 16) & 255), (float)(cv >> 24)};
#pragma unroll
        for (int e = 0; e < 4; e++) {
            float u = (xs[e] - muf) * istd;
#pragma unroll
            for (int k = 0; k < 7; k++) {
                float t = u - (float)(k - 3);
                acc[k] += cf[e] * __builtin_exp2f(C1 * t * t);
            }
        }
    }

    __shared__ float part[16][7];
    int wid = tid >> 6;
#pragma unroll
    for (int j = 0; j < 7; j++) {
        float v = acc[j];
#pragma unroll
        for (int o = 32; o > 0; o >>= 1) v += __shfl_down(v, o);
        if ((tid & 63) == 0) part[wid][j] = v;
    }
    __syncthreads();
    if (tid < 7) {
        float v = 0.f;
#pragma unroll
        for (int i = 0; i < 16; i++) v += part[i][tid];
        sample[w * 7 + tid] = v;
    }
}

// ---------------------------------------------------------------------------
// K4: final loss. Normalize per-(c,d) 7-bin histogram, smooth-L1 vs fixed
// target, gate by n>=1000, average over active classes. Single block.
// ---------------------------------------------------------------------------
__global__ __launch_bounds__(512) void hl_loss_kernel(
    const float* __restrict__ sample, const int* __restrict__ ncls,
    float* __restrict__ out)
{
    int tid = threadIdx.x;

    float targ[7];
    {
        double e[7], z = 0.0;
#pragma unroll
        for (int k = -3; k <= 3; k++) { e[k + 3] = exp(-0.5 * (double)(k * k)); z += e[k + 3]; }
#pragma unroll
        for (int j = 0; j < 7; j++) targ[j] = (float)(e[j] / z);
    }

    float lsum = 0.f, asum = 0.f;
    for (int p = tid; p < NPAIR; p += 512) {
        int c = p >> 6;
        int n = ncls[c];
        if (n < 1000) continue;             // inactive: contributes 0
        float sv[7], S = 0.f;
#pragma unroll
        for (int j = 0; j < 7; j++) { sv[j] = sample[p * 7 + j]; S += sv[j]; }
        float Ss = fmaxf(S, 1e-30f);
        float ps = 0.f;
#pragma unroll
        for (int j = 0; j < 7; j++) {
            float dd = fabsf(sv[j] / Ss - targ[j]);
            ps += (dd < 1.f) ? 0.5f * dd * dd : (dd - 0.5f);
        }
        lsum += ps;
        if ((p & 63) == 0) asum += 1.f;     // count each active class once (d==0)
    }

#pragma unroll
    for (int o = 32; o > 0; o >>= 1) {
        lsum += __shfl_down(lsum, o);
        asum += __shfl_down(asum, o);
    }
    __shared__ float lw[8], aw[8];
    int wid = tid >> 6;
    if ((tid & 63) == 0) { lw[wid] = lsum; aw[wid] = asum; }
    __syncthreads();
    if (tid == 0) {
        float L = 0.f, A = 0.f;
#pragma unroll
        for (int i = 0; i < 8; i++) { L += lw[i]; A += aw[i]; }
        out[0] = (A > 0.f) ? (L / 448.0f) / A : 0.0f;  // mean over D*7=448, /num_active
    }
}

// ---------------------------------------------------------------------------
extern "C" void kernel_launch(void* const* d_in, const int* in_sizes, int n_in,
                              void* d_out, int out_size, void* d_ws, size_t ws_size,
                              hipStream_t stream)
{
    const float* feature = (const float*)d_in[0];   // [1,64,128,128] fp32
    const int*   label   = (const int*)d_in[1];     // [1,1,512,512]  int32
    float*       out     = (float*)d_out;           // scalar fp32

    char* ws = (char*)d_ws;
    unsigned char* cnt    = (unsigned char*)(ws);                   // 311296 B
    double*        S1     = (double*)(ws + 311296);                 // 9728 B
    double*        S2     = (double*)(ws + 311296 + 9728);          // 9728 B
    int*           ncls   = (int*)(ws + 311296 + 2 * 9728);         // 76 B
    float*         sample = (float*)(ws + 311296 + 2 * 9728 + 128); // 34048 B

    hl_count_kernel<<<SRC / 256, 256, 0, stream>>>(label, cnt);
    hl_moments_kernel<<<NPAIR, 1024, 0, stream>>>(feature, cnt, S1, S2, ncls);
    hl_kde_kernel<<<NPAIR, 1024, 0, stream>>>(feature, cnt, S1, S2, ncls, sample);
    hl_loss_kernel<<<1, 512, 0, stream>>>(sample, ncls, out);
}

// Round 3
// 96.705 us; speedup vs baseline: 2.2573x; 1.1375x over previous
//
#include <hip/hip_runtime.h>
#include <hip/hip_bf16.h>

// Problem constants
#define SRC   16384      // 128*128 source pixels
#define DCH   64         // channels
#define NCLS  19         // classes
#define NPAIR (NCLS*DCH) // 1216 (c,d) pairs
#define KSPLIT 2         // pixel-split blocks per pair in the KDE kernel

// Bare v_exp_f32: args here are in [-450, 0]; denormal-guard sequence is
// pure overhead (underflow->0 matches the reference's f32 exp behavior).
#if defined(__has_builtin)
#if __has_builtin(__builtin_amdgcn_exp2f)
#define EXP2F(x) __builtin_amdgcn_exp2f(x)
#else
#define EXP2F(x) __builtin_exp2f(x)
#endif
#else
#define EXP2F(x) __builtin_exp2f(x)
#endif

// ---------------------------------------------------------------------------
// K1: per-source-pixel class counts. Each source pixel covers a 4x4 block of
// the 512x512 label map. cnt[c*SRC + s] = #subpixels with label c (0..16).
// ---------------------------------------------------------------------------
__global__ __launch_bounds__(256) void hl_count_kernel(
    const int* __restrict__ label, unsigned char* __restrict__ cnt)
{
    int s  = blockIdx.x * 256 + threadIdx.x;   // 64 blocks x 256 = 16384
    int sy = s >> 7, sx = s & 127;
    const int4* lab4 = (const int4*)label;
    int l[16];
#pragma unroll
    for (int r = 0; r < 4; r++) {
        int4 v = lab4[(4 * sy + r) * 128 + sx];
        l[4 * r + 0] = v.x; l[4 * r + 1] = v.y;
        l[4 * r + 2] = v.z; l[4 * r + 3] = v.w;
    }
#pragma unroll
    for (int c = 0; c < NCLS; c++) {
        int cc = 0;
#pragma unroll
        for (int j = 0; j < 16; j++) cc += (l[j] == c) ? 1 : 0;
        cnt[c * SRC + s] = (unsigned char)cc;
    }
}

// ---------------------------------------------------------------------------
// K2: per-(class,channel) moments. One 1024-thread block per (c,d).
// fp32 per-thread partials (16 px), f64 only in the cross-lane reduction
// (partials are short sums; total rel err ~1e-7, budget ~2e-2).
// ---------------------------------------------------------------------------
__global__ __launch_bounds__(1024) void hl_moments_kernel(
    const float* __restrict__ feature, const unsigned char* __restrict__ cnt,
    double* __restrict__ S1, double* __restrict__ S2, int* __restrict__ ncls)
{
    int w = blockIdx.x;             // pair index 0..1215
    int c = w >> 6, d = w & 63;
    int tid = threadIdx.x;

    const float4*       fp4 = (const float4*)(feature + d * SRC);
    const unsigned int* cp4 = (const unsigned int*)(cnt + c * SRC);

    float f1 = 0.f, f2 = 0.f;
    int   nc = 0;
#pragma unroll
    for (int i = 0; i < 4; i++) {
        int g = i * 1024 + tid;      // 4096 groups of 4 pixels
        float4       x  = fp4[g];
        unsigned int cv = cp4[g];
        float xs[4] = {x.x, x.y, x.z, x.w};
        float cf[4] = {(float)(cv & 255u), (float)((cv >> 8) & 255u),
                       (float)((cv >> 16) & 255u), (float)(cv >> 24)};
#pragma unroll
        for (int e = 0; e < 4; e++) {
            float wx = cf[e] * xs[e];
            f1 += wx;
            f2 = fmaf(wx, xs[e], f2);
        }
        nc += (cv & 255u) + ((cv >> 8) & 255u) + ((cv >> 16) & 255u) + (cv >> 24);
    }
    double s1 = (double)f1, s2 = (double)f2;
#pragma unroll
    for (int o = 32; o > 0; o >>= 1) {
        s1 += __shfl_down(s1, o);
        s2 += __shfl_down(s2, o);
        nc += __shfl_down(nc, o);
    }
    __shared__ double ps1[16], ps2[16];
    __shared__ int    pn[16];
    int wid = tid >> 6;
    if ((tid & 63) == 0) { ps1[wid] = s1; ps2[wid] = s2; pn[wid] = nc; }
    __syncthreads();
    if (tid == 0) {
        double a = 0.0, b = 0.0; int n = 0;
#pragma unroll
        for (int i = 0; i < 16; i++) { a += ps1[i]; b += ps2[i]; n += pn[i]; }
        S1[w] = a; S2[w] = b;
        if (d == 0) ncls[c] = n;
    }
}

// ---------------------------------------------------------------------------
// K3: KDE. KSPLIT blocks per (c,d), each covering SRC/KSPLIT pixels.
// C1*(u-k)^2 = q - 2k*p + C1*k^2 with p = C1*u, q = p*u  (2 ops/bin + exp).
// The 1/sqrt(2*pi*var_s) factor cancels in downstream normalization.
// Deterministic: each block writes its own 7-slot partial.
// ---------------------------------------------------------------------------
__global__ __launch_bounds__(1024) void hl_kde_kernel(
    const float* __restrict__ feature, const unsigned char* __restrict__ cnt,
    const double* __restrict__ S1d, const double* __restrict__ S2d,
    const int* __restrict__ ncls, float* __restrict__ sample)
{
    int blk  = blockIdx.x;          // 0..NPAIR*KSPLIT-1
    int w    = blk >> 1;            // pair
    int half = blk & 1;
    int c = w >> 6, d = w & 63;
    int tid = threadIdx.x;

    __shared__ float sh_mu, sh_istd;
    if (tid == 0) {
        int    n     = ncls[c];
        double nsafe = (n > 0) ? (double)n : 1.0;
        double s1 = S1d[w], s2 = S2d[w];
        double mu  = s1 / nsafe;
        double var = (s2 - 2.0 * mu * s1 + mu * mu * (double)n) / nsafe + 1e-10;
        sh_mu   = (float)mu;
        sh_istd = (float)(1.0 / sqrt(var));
    }
    __syncthreads();
    float istd = sh_istd;
    float nm   = -sh_mu * istd;     // u = fma(x, istd, nm)

    const float4*       fp4 = (const float4*)(feature + d * SRC);
    const unsigned int* cp4 = (const unsigned int*)(cnt + c * SRC);

    const float C1 = -18.033688011112042f;   // -12.5 * log2(e)
    float acc[7] = {0.f, 0.f, 0.f, 0.f, 0.f, 0.f, 0.f};

#pragma unroll
    for (int i = 0; i < 2; i++) {
        int g = half * 2048 + i * 1024 + tid;   // 2048 float4-groups per block
        float4       x  = fp4[g];
        unsigned int cv = cp4[g];
        float xs[4] = {x.x, x.y, x.z, x.w};
        float cf[4] = {(float)(cv & 255u), (float)((cv >> 8) & 255u),
                       (float)((cv >> 16) & 255u), (float)(cv >> 24)};
#pragma unroll
        for (int e = 0; e < 4; e++) {
            float u = fmaf(xs[e], istd, nm);
            float p = C1 * u;
            float q = p * u;                     // C1*u^2
#pragma unroll
            for (int k = 0; k < 7; k++) {
                float km = (float)(k - 3);
                float arg = fmaf(p, -2.f * km, q + C1 * km * km);
                acc[k] = fmaf(cf[e], EXP2F(arg), acc[k]);
            }
        }
    }

    __shared__ float part[16][7];
    int wid = tid >> 6;
#pragma unroll
    for (int j = 0; j < 7; j++) {
        float v = acc[j];
#pragma unroll
        for (int o = 32; o > 0; o >>= 1) v += __shfl_down(v, o);
        if ((tid & 63) == 0) part[wid][j] = v;
    }
    __syncthreads();
    if (tid < 7) {
        float v = 0.f;
#pragma unroll
        for (int i = 0; i < 16; i++) v += part[i][tid];
        sample[blk * 7 + tid] = v;
    }
}

// ---------------------------------------------------------------------------
// K4: final loss. Combine the KSPLIT partials, normalize, smooth-L1 vs the
// fixed target, gate by n>=1000, average over active classes. Single block.
// ---------------------------------------------------------------------------
__global__ __launch_bounds__(512) void hl_loss_kernel(
    const float* __restrict__ sample, const int* __restrict__ ncls,
    float* __restrict__ out)
{
    int tid = threadIdx.x;

    float targ[7];
    {
        double e[7], z = 0.0;
#pragma unroll
        for (int k = -3; k <= 3; k++) { e[k + 3] = exp(-0.5 * (double)(k * k)); z += e[k + 3]; }
#pragma unroll
        for (int j = 0; j < 7; j++) targ[j] = (float)(e[j] / z);
    }

    float lsum = 0.f, asum = 0.f;
    for (int p = tid; p < NPAIR; p += 512) {
        int c = p >> 6;
        int n = ncls[c];
        if (n < 1000) continue;             // inactive: contributes 0
        float sv[7], S = 0.f;
#pragma unroll
        for (int j = 0; j < 7; j++) {
            sv[j] = sample[(2 * p) * 7 + j] + sample[(2 * p + 1) * 7 + j];
            S += sv[j];
        }
        float Ss = fmaxf(S, 1e-30f);
        float ps = 0.f;
#pragma unroll
        for (int j = 0; j < 7; j++) {
            float dd = fabsf(sv[j] / Ss - targ[j]);
            ps += (dd < 1.f) ? 0.5f * dd * dd : (dd - 0.5f);
        }
        lsum += ps;
        if ((p & 63) == 0) asum += 1.f;     // count each active class once (d==0)
    }

#pragma unroll
    for (int o = 32; o > 0; o >>= 1) {
        lsum += __shfl_down(lsum, o);
        asum += __shfl_down(asum, o);
    }
    __shared__ float lw[8], aw[8];
    int wid = tid >> 6;
    if ((tid & 63) == 0) { lw[wid] = lsum; aw[wid] = asum; }
    __syncthreads();
    if (tid == 0) {
        float L = 0.f, A = 0.f;
#pragma unroll
        for (int i = 0; i < 8; i++) { L += lw[i]; A += aw[i]; }
        out[0] = (A > 0.f) ? (L / 448.0f) / A : 0.0f;  // mean over D*7=448, /num_active
    }
}

// ---------------------------------------------------------------------------
extern "C" void kernel_launch(void* const* d_in, const int* in_sizes, int n_in,
                              void* d_out, int out_size, void* d_ws, size_t ws_size,
                              hipStream_t stream)
{
    const float* feature = (const float*)d_in[0];   // [1,64,128,128] fp32
    const int*   label   = (const int*)d_in[1];     // [1,1,512,512]  int32
    float*       out     = (float*)d_out;           // scalar fp32

    char* ws = (char*)d_ws;
    unsigned char* cnt    = (unsigned char*)(ws);                   // 311296 B
    double*        S1     = (double*)(ws + 311296);                 // 9728 B
    double*        S2     = (double*)(ws + 311296 + 9728);          // 9728 B
    int*           ncls   = (int*)(ws + 311296 + 2 * 9728);         // 76 B (pad 128)
    float*         sample = (float*)(ws + 311296 + 2 * 9728 + 128); // 2432*7*4 = 68096 B

    hl_count_kernel<<<SRC / 256, 256, 0, stream>>>(label, cnt);
    hl_moments_kernel<<<NPAIR, 1024, 0, stream>>>(feature, cnt, S1, S2, ncls);
    hl_kde_kernel<<<NPAIR * KSPLIT, 1024, 0, stream>>>(feature, cnt, S1, S2, ncls, sample);
    hl_loss_kernel<<<1, 512, 0, stream>>>(sample, ncls, out);
}